// Round 2
// baseline (1057.577 us; speedup 1.0000x reference)
//
#include <hip/hip_runtime.h>
#include <stdint.h>
#include <stddef.h>

// ---------------------------------------------------------------------------
// Round 9: R8's 256x256 / BK=64 / 8-wave / 4-phase counted-vmcnt pipeline,
// with the frag loads converted to INLINE-ASM ds_read_b128 + manual
// lgkmcnt(0) + sched_barrier(0) (rule #18). Rationale: R8's plain-deref LDS
// reads alias the global_load_lds destinations, so the compiler's waitcnt
// pass inserts conservative vmcnt drains every phase, collapsing the 6-deep
// in-flight ledger (observed ~3k stall cyc/K-tile, MfmaUtil 26%). Asm reads
// are invisible to that pass; ordering is provided manually. k-loop fully
// unrolled (compile-time buffer parity, folded guards); GATHER indices
// preloaded to static-indexed VGPRs so the main loop has zero
// compiler-visible LDS reads.
// ---------------------------------------------------------------------------

typedef __attribute__((ext_vector_type(8))) short short8;
typedef __attribute__((ext_vector_type(4))) float floatv4;
typedef __attribute__((ext_vector_type(8))) unsigned short ushort8;

#define GLOAD_LDS16(g, l)                                                      \
  __builtin_amdgcn_global_load_lds(                                            \
      (const __attribute__((address_space(1))) void*)(g),                      \
      (__attribute__((address_space(3))) void*)(l), 16, 0, 0)

__device__ __forceinline__ unsigned short f2bf(float f) {
  unsigned int u = __float_as_uint(f);
  u += 0x7fffu + ((u >> 16) & 1u);  // RNE
  return (unsigned short)(u >> 16);
}
__device__ __forceinline__ float bf2f(unsigned short s) {
  return __uint_as_float(((unsigned int)s) << 16);
}

#define NNODES 100000
#define MTOT   300000
#define HD     512
#define NH     50000
#define LSTR   264   // epilogue L row stride in shorts: 528B = 33 x 16B (odd)

// --- Wt plain panel layout: [layer][cb*8+kt][row 0..255][g 0..7][e 0..7] ----
__global__ __launch_bounds__(256) void prep_w(const float* __restrict__ W1,
                                              const float* __restrict__ W2,
                                              const float* __restrict__ W3,
                                              unsigned short* __restrict__ Wt) {
  int t = blockIdx.x * 256 + threadIdx.x;  // < 3*512*512
  int layer = t >> 18;
  int r = t & 262143;
  int e = r & 7;
  int g = (r >> 3) & 7;
  int row = (r >> 6) & 255;
  int cbkt = r >> 14;  // 0..15
  int cb = cbkt >> 3, kt = cbkt & 7;
  int n = cb * 256 + row;
  int k = kt * 64 + g * 8 + e;
  const float* W = layer == 0 ? W1 : (layer == 1 ? W2 : W3);
  Wt[t] = f2bf(W[k * 512 + n]);
}

// --- hb = bf16(h) [50000 x 128], row-major ----------------------------------
__global__ __launch_bounds__(256) void prep_hb(const float* __restrict__ h,
                                               unsigned short* __restrict__ hb) {
  int t = blockIdx.x * 256 + threadIdx.x;  // < NH*16
  int v = t >> 4, c8 = (t & 15) * 8;
  const floatv4* hp = (const floatv4*)(h + (size_t)v * 128 + c8);
  floatv4 f0 = hp[0], f1 = hp[1];
  ushort8 o;
#pragma unroll
  for (int e = 0; e < 4; ++e) {
    o[e] = f2bf(f0[e]);
    o[4 + e] = f2bf(f1[e]);
  }
  *(ushort8*)(hb + (size_t)v * 128 + c8) = o;
}

__global__ __launch_bounds__(256) void init_out(float* __restrict__ out,
                                                const float* __restrict__ bo) {
  int t = blockIdx.x * 256 + threadIdx.x;
  if (t < 2 * NNODES) out[t] = bo[t & 1];
}

// ---------------------------------------------------------------------------
// GEMM: 256x256 tile, BK=64, K=512 (8 K-tiles), 512 thr, 16x16x32 MFMA.
// LDS: A0@0 A1@32K B0@64K B1@96K (each 32KB, row-major [256][64] bf16 with
// 16B-granule XOR (g ^ row&7) at source+read). Epilogue L overlays
// [0,135168); sIdx@135168 (GATHER), sWo@139264 (FINAL).
// ---------------------------------------------------------------------------

#define BAR()                            \
  __builtin_amdgcn_sched_barrier(0);     \
  __builtin_amdgcn_s_barrier();          \
  __builtin_amdgcn_sched_barrier(0)

#define WAIT_LGKM()                                    \
  asm volatile("s_waitcnt lgkmcnt(0)" ::: "memory");   \
  __builtin_amdgcn_sched_barrier(0)

#define DSR(dst, ad) asm volatile("ds_read_b128 %0, %1" : "=v"(dst) : "v"(ad))

#define STAGE_A(kk, odd)                                                       \
  {                                                                            \
    char* db = smem + ((kk) & 1) * 32768;                                      \
    _Pragma("unroll")                                                          \
    for (int qq = 0; qq < 2; ++qq) {                                           \
      int q = (odd) + qq * 2;                                                  \
      const unsigned short* sp;                                                \
      if (GATHER) {                                                            \
        sp = A + (size_t)gidx[q][(kk) >> 1] * 128 + ((kk) & 1) * 64 + sxg * 8; \
      } else {                                                                 \
        int row = q * 64 + tr;                                                 \
        sp = A + (((size_t)(rb * 8 + (kk)) * 256 + row) * 8 + sxg) * 8;        \
      }                                                                        \
      GLOAD_LDS16(sp, db + q * 8192 + t * 16);                                 \
    }                                                                          \
  }

#define STAGE_B(kk, odd)                                                       \
  {                                                                            \
    char* db = smem + 65536 + ((kk) & 1) * 32768;                              \
    _Pragma("unroll")                                                          \
    for (int qq = 0; qq < 2; ++qq) {                                           \
      int q = (odd) + qq * 2;                                                  \
      const unsigned short* sp =                                               \
          Wt + (((size_t)(cb * 8 + (kk)) * 256 + q * 64 + tr) * 8 + sxg) * 8;  \
      GLOAD_LDS16(sp, db + q * 8192 + t * 16);                                 \
    }                                                                          \
  }

#define LDA(mh)                                                                \
  _Pragma("unroll")                                                            \
  for (int mi = 0; mi < 4; ++mi) {                                             \
    unsigned ra_ =                                                             \
        aOff + (unsigned)((wmbase + (mh) * 64 + mi * 16 + lr) * 128);          \
    DSR(a[mi][0], ra_ + (unsigned)xb0);                                        \
    DSR(a[mi][1], ra_ + (unsigned)xb1);                                        \
  }

#define LDB(nh)                                                                \
  _Pragma("unroll")                                                            \
  for (int nj = 0; nj < 2; ++nj) {                                             \
    unsigned rb_ =                                                             \
        bOff + (unsigned)((wnbase + (nh) * 32 + nj * 16 + lr) * 128);          \
    DSR(b[(nh)*2 + nj][0], rb_ + (unsigned)xb0);                               \
    DSR(b[(nh)*2 + nj][1], rb_ + (unsigned)xb1);                               \
  }

#define MMA(mh, nh)                                                            \
  __builtin_amdgcn_s_setprio(1);                                               \
  _Pragma("unroll")                                                            \
  for (int mi = 0; mi < 4; ++mi)                                               \
    _Pragma("unroll")                                                          \
    for (int nj = 0; nj < 2; ++nj) {                                           \
      acc[(mh) * 4 + mi][(nh) * 2 + nj] =                                      \
          __builtin_amdgcn_mfma_f32_16x16x32_bf16(                             \
              a[mi][0], b[(nh) * 2 + nj][0],                                   \
              acc[(mh) * 4 + mi][(nh) * 2 + nj], 0, 0, 0);                     \
      acc[(mh) * 4 + mi][(nh) * 2 + nj] =                                      \
          __builtin_amdgcn_mfma_f32_16x16x32_bf16(                             \
              a[mi][1], b[(nh) * 2 + nj][1],                                   \
              acc[(mh) * 4 + mi][(nh) * 2 + nj], 0, 0, 0);                     \
    }                                                                          \
  __builtin_amdgcn_s_setprio(0);

template <int GATHER, int FINAL>
__global__ __launch_bounds__(512, 2) void gemm_k(
    const unsigned short* __restrict__ A,   // GATHER ? hb(row-major) : X panel
    const int* __restrict__ idx,
    const unsigned short* __restrict__ Wt,  // plain panel layout
    const float* __restrict__ bias,
    unsigned short* __restrict__ Xout,      // plain panel layout
    float* __restrict__ out, const float* __restrict__ Wo,
    int mchunk0) {
  __shared__ __align__(16) char smem[141312];
  int* sIdx = (int*)(smem + 135168);
  float* sWo = (float*)(smem + 139264);

  const int t = threadIdx.x;
  int bx = blockIdx.x;
  // XCD swizzle (grid is a multiple of 48, hence of 8); the 2 col-blocks of
  // one row-block are adjacent -> same XCD chunk (shared A panel in L2).
  int cpx = (int)gridDim.x >> 3;
  int wg = (bx & 7) * cpx + (bx >> 3);
  int cb = wg & 1;
  int rb = wg >> 1;
  int n0 = cb * 256;

  const int l = t & 63;
  const int w = t >> 6;
  const int wmbase = (w >> 2) * 128;  // 2 warp-rows
  const int wnbase = (w & 3) * 64;    // 4 warp-cols
  const int lr = l & 15, lk = l >> 4;
  const int xb0 = (lk ^ (lr & 7)) * 16;  // ks=0 granule byte (XOR swizzle)
  const int xb1 = xb0 ^ 64;              // ks=1: granule ^= 4
  const int tr = t >> 3;                 // staging row-in-quarter
  const int sxg = (t & 7) ^ (tr & 7);    // staging source granule (inv XOR)

  const unsigned offA =
      (unsigned)(size_t)(__attribute__((address_space(3))) char*)smem;
  const unsigned offB = offA + 65536u;

  if (FINAL) sWo[t] = Wo[n0 * 2 + t];

  int gidx[4][4];
  if (GATHER) {
    if (t < 256) {
      int m = mchunk0 + rb * 256 + t;
      unsigned um = (unsigned)m;
      unsigned n = um / 3u;
      int p = (int)(um - n * 3u);
      if (n >= (unsigned)NNODES) n = 0;  // padded tail: junk, guarded at out
      const unsigned pk0 = 0x320u, pk1 = 0x111u, pk2 = 0x032u, pk3 = 0x203u;
      int sh = p * 4;
      sIdx[t * 4 + 0] = idx[n * 4 + ((pk0 >> sh) & 0xFu)];
      sIdx[t * 4 + 1] = idx[n * 4 + ((pk1 >> sh) & 0xFu)];
      sIdx[t * 4 + 2] = idx[n * 4 + ((pk2 >> sh) & 0xFu)];
      sIdx[t * 4 + 3] = idx[n * 4 + ((pk3 >> sh) & 0xFu)];
    }
    __syncthreads();
    // preload this thread's 16 gather indices into static-indexed VGPRs so
    // the main loop has no compiler-visible LDS reads.
#pragma unroll
    for (int q = 0; q < 4; ++q)
#pragma unroll
      for (int jb = 0; jb < 4; ++jb) gidx[q][jb] = sIdx[(q * 64 + tr) * 4 + jb];
  }

  floatv4 acc[8][4];
#pragma unroll
  for (int i = 0; i < 8; ++i)
#pragma unroll
    for (int j = 0; j < 4; ++j)
#pragma unroll
      for (int r = 0; r < 4; ++r) acc[i][j][r] = 0.f;

  // Prologue: K-tile0 fully (8 loads/thr) + K-tile1 {A-even,B-even,B-odd}.
  // vmcnt(6) completes exactly K-tile0; the 6 K-tile1 loads stay in flight.
  STAGE_A(0, 0); STAGE_A(0, 1); STAGE_B(0, 0); STAGE_B(0, 1);
  STAGE_A(1, 0); STAGE_B(1, 0); STAGE_B(1, 1);
  asm volatile("s_waitcnt vmcnt(6)" ::: "memory");
  BAR();

  // Main loop, FULLY unrolled (k compile-time: folded guards, static gidx).
  // Ledger: before iter-k's p4 wait, outstanding = 14 loads (7 chunks);
  // vmcnt(6) completes the 8 oldest = ALL of K-tile k+1, leaves k+2's
  // {A-even,B-even,B-odd} (6 loads) in flight across the barriers.
#pragma unroll
  for (int k = 0; k < 8; ++k) {
    const unsigned aOff = offA + (unsigned)((k & 1) * 32768);
    const unsigned bOff = offB + (unsigned)((k & 1) * 32768);
    short8 a[4][2], b[4][2];
    // ---- phase 1: quad (0,0); stage A-odd(k+1) into other buffer
    LDA(0);
    LDB(0);
    if (k < 7) STAGE_A(k + 1, 1);
    BAR();
    WAIT_LGKM();
    MMA(0, 0);
    BAR();
    // ---- phase 2: quad (0,1); stage A-even(k+2) (A-even(k) consumed @p1)
    LDB(1);
    if (k < 6) STAGE_A(k + 2, 0);
    BAR();
    WAIT_LGKM();
    MMA(0, 1);
    BAR();
    // ---- phase 3: quad (1,0); stage B-even(k+2) (all B consumed by p2)
    LDA(1);
    if (k < 6) STAGE_B(k + 2, 0);
    BAR();
    WAIT_LGKM();
    MMA(1, 0);
    BAR();
    // ---- phase 4: quad (1,1); stage B-odd(k+2); counted drain
    if (k < 6) STAGE_B(k + 2, 1);
    BAR();
    MMA(1, 1);
    if (k < 6) {
      asm volatile("s_waitcnt vmcnt(6)" ::: "memory");
    } else {
      asm volatile("s_waitcnt vmcnt(0)" ::: "memory");
    }
    BAR();
  }

  // Epilogue. 16x16 C/D: col = lane&15, row = (lane>>4)*4 + reg.
  unsigned short* L = (unsigned short*)smem;
  {
    float bv[4];
#pragma unroll
    for (int nj = 0; nj < 4; ++nj) bv[nj] = bias[n0 + wnbase + nj * 16 + lr];
#pragma unroll
    for (int mi = 0; mi < 8; ++mi)
#pragma unroll
      for (int nj = 0; nj < 4; ++nj) {
        int col = wnbase + nj * 16 + lr;
#pragma unroll
        for (int r = 0; r < 4; ++r) {
          int row = wmbase + mi * 16 + lk * 4 + r;
          float v = fmaxf(acc[mi][nj][r] + bv[nj], 0.f);
          L[row * LSTR + col] = f2bf(v);
        }
      }
  }
  __syncthreads();

  if (!FINAL) {
    // plain panel-order stores: consecutive t -> consecutive 16B slots
#pragma unroll
    for (int it = 0; it < 16; ++it) {
      int slot = it * 512 + t;  // 0..8191
      int ktq = slot >> 11;     // local k-tile 0..3
      int s = slot & 2047;
      int row = s >> 3, g = s & 7;
      ushort8 val = *(const ushort8*)(L + row * LSTR + ktq * 64 + g * 8);
      *(ushort8*)(Xout +
                  ((size_t)((rb * 8 + cb * 4 + ktq) * 256 + row) * 8 + g) * 8) =
          val;
    }
  } else {
    int r2 = t >> 1, jo = t & 1;
    int grow = mchunk0 + rb * 256 + r2;
    if (grow < MTOT) {
      const unsigned short* Lr = L + r2 * LSTR;
      float s = 0.f;
#pragma unroll
      for (int cc = 0; cc < 256; cc += 2) {
        unsigned int pair = *(const unsigned int*)(Lr + cc);
        s += bf2f((unsigned short)(pair & 0xffffu)) * sWo[2 * cc + jo];
        s += bf2f((unsigned short)(pair >> 16)) * sWo[2 * cc + 2 + jo];
      }
      int node = grow / 3;
      atomicAdd(out + node * 2 + jo, s);
    }
  }
}

extern "C" void kernel_launch(void* const* d_in, const int* in_sizes, int n_in,
                              void* d_out, int out_size, void* d_ws,
                              size_t ws_size, hipStream_t stream) {
  const float* h  = (const float*)d_in[0];
  const int*   ix = (const int*)d_in[1];
  const float* W1 = (const float*)d_in[2];
  const float* b1 = (const float*)d_in[3];
  const float* W2 = (const float*)d_in[4];
  const float* b2 = (const float*)d_in[5];
  const float* W3 = (const float*)d_in[6];
  const float* b3 = (const float*)d_in[7];
  const float* Wo = (const float*)d_in[8];
  const float* bo = (const float*)d_in[9];
  float* out = (float*)d_out;

  unsigned short* ws = (unsigned short*)d_ws;
  unsigned short* Wt = ws;                  // 3*512*512 shorts (panel)
  unsigned short* hb = Wt + 786432;         // 50000*128 shorts (row-major)
  unsigned short* bufs = hb + 6400000;
  const size_t baseBytes = (786432ull + 6400000ull) * 2;

  // nodes per chunk: multiple of 2048 -> rows%6144==0 -> RB%24==0, grid%48==0
  size_t avail = ws_size > baseBytes ? ws_size - baseBytes : 0;
  size_t ncap = avail / (2ull * 3 * HD * sizeof(unsigned short));
  size_t nc = (ncap / 2048) * 2048;
  if (nc > 32768) nc = 32768;
  if (nc == 0) nc = 2048;  // best effort
  unsigned short* X1 = bufs;                // panel layout
  unsigned short* X2 = X1 + nc * 3 * HD;    // panel layout

  prep_w<<<3072, 256, 0, stream>>>(W1, W2, W3, Wt);
  prep_hb<<<NH * 16 / 256, 256, 0, stream>>>(h, hb);
  init_out<<<(2 * NNODES + 255) / 256, 256, 0, stream>>>(out, bo);

  for (size_t n0c = 0; n0c < NNODES; n0c += nc) {
    size_t remn = (size_t)NNODES - n0c;
    size_t ncp = remn < nc ? ((remn + 2047) / 2048) * 2048 : nc;
    int rows = (int)(ncp * 3);
    int RB = rows / 256;
    int m0 = (int)(3 * n0c);
    gemm_k<1, 0><<<RB * 2, 512, 0, stream>>>(hb, ix, Wt, b1, X1, nullptr,
                                             nullptr, m0);
    gemm_k<0, 0><<<RB * 2, 512, 0, stream>>>(X1, nullptr, Wt + 262144, b2, X2,
                                             nullptr, nullptr, m0);
    gemm_k<0, 1><<<RB * 2, 512, 0, stream>>>(X2, nullptr, Wt + 524288, b3,
                                             nullptr, out, Wo, m0);
  }
}

// Round 3
// 749.764 us; speedup vs baseline: 1.4105x; 1.4105x over previous
//
#include <hip/hip_runtime.h>
#include <stdint.h>
#include <stddef.h>

// ---------------------------------------------------------------------------
// Round 10: revert to the proven R7 2-barrier structure (R8/R9's deep
// pipeline falsified here: K=512 -> 8 K-tiles, 1 block/CU -> fill/drain and
// serial prologue/epilogue dominate). R7 is LDS-BW-bound (MfmaUtil 30%,
// ~750-1500 LDS cyc vs 512 matrix cyc per CU-kt). Fix: in the two DENSE
// gemms, widen per-wave A-rows (A is direct-from-global, costs no LDS):
// BM=256 x BN=128, 4 waves, per-wave 128x64 -> 32 MFMA per kt per wave
// against the same 8 B-frag ds_read_b128 -> LDS-read per MFMA halves.
// GATHER gemm1 stays exactly R7 (128x128, LDS-staged gather A).
// X inter-layer layout: 256-row panels, slot(kt,ks,rg8,half,m32) so dense
// A-frag loads are lane-contiguous 1KB dwordx4. Dense epilogue: two 128-row
// passes (LDS stays 36KB).
// ---------------------------------------------------------------------------

typedef __attribute__((ext_vector_type(8))) short short8;
typedef __attribute__((ext_vector_type(16))) float f32x16;
typedef __attribute__((ext_vector_type(4))) float floatv4;
typedef __attribute__((ext_vector_type(8))) unsigned short ushort8;

#define GLOAD_LDS16(g, l)                                                      \
  __builtin_amdgcn_global_load_lds(                                            \
      (const __attribute__((address_space(1))) void*)(g),                      \
      (__attribute__((address_space(3))) void*)(l), 16, 0, 0)

__device__ __forceinline__ unsigned short f2bf(float f) {
  unsigned int u = __float_as_uint(f);
  u += 0x7fffu + ((u >> 16) & 1u);  // RNE
  return (unsigned short)(u >> 16);
}
__device__ __forceinline__ float bf2f(unsigned short s) {
  return __uint_as_float(((unsigned int)s) << 16);
}

#define NNODES 100000
#define MTOT   300000
#define HD     512
#define NH     50000
#define LSTR   152   // gather epilogue L stride (shorts): 304B = 19 x 16B
#define LSTR2  136   // dense epilogue L stride (shorts): 272B = 17 x 16B

// --- Wt panel layout (R7): per layer, per (nb,kt) panel of 1024 16B-slots ---
// slot s = (c>>1)*256 + ((n>>5)&3)*64 + (c&1)*32 + (n&31), c=k-granule 0..7
__global__ __launch_bounds__(256) void prep_w(const float* __restrict__ W1,
                                              const float* __restrict__ W2,
                                              const float* __restrict__ W3,
                                              unsigned short* __restrict__ Wt) {
  int t = blockIdx.x * 256 + threadIdx.x;  // < 3*512*512
  int layer = t >> 18;
  int r = t & 262143;
  int e = r & 7;
  int q16 = r >> 3;
  int s = q16 & 1023;
  int blk = q16 >> 10;        // 0..31
  int nb = blk >> 3, kt = blk & 7;
  int c = ((s >> 8) << 1) | ((s >> 5) & 1);
  int row = ((s >> 6) & 3) * 32 + (s & 31);
  int n = nb * 128 + row;
  int k = kt * 64 + c * 8 + e;
  const float* W = layer == 0 ? W1 : (layer == 1 ? W2 : W3);
  Wt[t] = f2bf(W[k * 512 + n]);
}

// --- hb = bf16(h) [50000 x 128], row-major ----------------------------------
__global__ __launch_bounds__(256) void prep_hb(const float* __restrict__ h,
                                               unsigned short* __restrict__ hb) {
  int t = blockIdx.x * 256 + threadIdx.x;  // < NH*16
  int v = t >> 4, c8 = (t & 15) * 8;
  const floatv4* hp = (const floatv4*)(h + (size_t)v * 128 + c8);
  floatv4 f0 = hp[0], f1 = hp[1];
  ushort8 o;
#pragma unroll
  for (int e = 0; e < 4; ++e) {
    o[e] = f2bf(f0[e]);
    o[4 + e] = f2bf(f1[e]);
  }
  *(ushort8*)(hb + (size_t)v * 128 + c8) = o;
}

__global__ __launch_bounds__(256) void init_out(float* __restrict__ out,
                                                const float* __restrict__ bo) {
  int t = blockIdx.x * 256 + threadIdx.x;
  if (t < 2 * NNODES) out[t] = bo[t & 1];
}

// ---------------------------------------------------------------------------
// X panel layout (256-row blocks): slot(mblk, kt, ks, rg8, half, m32) =
//   (mblk*8 + kt)*2048 + ks*512 + rg8*64 + half*32 + m32   (x8 shorts)
// holding X[m = mblk*256 + rg8*32 + m32][k = kt*64 + (ks*2+half)*8 + e].
// A-frag load for a wave row-group is then lane-contiguous (1KB dwordx4).
// ---------------------------------------------------------------------------

// --- GATHER gemm (layer 1): exact R7 structure, 128x128 tile, BK=64 --------
__global__ __launch_bounds__(256, 4) void gemm_g(
    const unsigned short* __restrict__ A,   // hb, row-major [NH][128]
    const int* __restrict__ idx,
    const unsigned short* __restrict__ Wt,  // R7 panel layout
    const float* __restrict__ bias,
    unsigned short* __restrict__ Xout,      // 256-row panel layout
    int mchunk0) {
  __shared__ __align__(16) char smem[39936];
  char* sB = smem;                       // 16384 (B tile, panel order)
  char* sA = smem + 16384;               // 16384 (row-major + XOR)
  int* sIdx = (int*)(smem + 32768);      // 2048
  // epilogue L overlays smem[0..38912)

  const int t = threadIdx.x;
  int bx = blockIdx.x;
  int xcd = bx & 7, tq = bx >> 3;
  int cbk = tq & 3;
  int rb = xcd + ((tq >> 2) << 3);
  int n0 = cbk * 128;
  int w = t >> 6, l = t & 63;
  int wmq = (w >> 1) * 2, wnq = (w & 1) * 2;
  int m32 = l & 31, half = l >> 5;
  int wm = wmq * 32;

  if (t < 128) {
    int m = mchunk0 + rb * 128 + t;
    unsigned um = (unsigned)m;
    unsigned n = um / 3u;
    int p = (int)(um - n * 3u);
    if (n >= NNODES) n = 0;  // padded tail rows: junk, guarded at output
    const unsigned pk0 = 0x320u, pk1 = 0x111u, pk2 = 0x032u, pk3 = 0x203u;
    int sh = p * 4;
    sIdx[t * 4 + 0] = idx[n * 4 + ((pk0 >> sh) & 0xFu)];
    sIdx[t * 4 + 1] = idx[n * 4 + ((pk1 >> sh) & 0xFu)];
    sIdx[t * 4 + 2] = idx[n * 4 + ((pk2 >> sh) & 0xFu)];
    sIdx[t * 4 + 3] = idx[n * 4 + ((pk3 >> sh) & 0xFu)];
  }
  __syncthreads();

  f32x16 acc[2][2];
#pragma unroll
  for (int i = 0; i < 2; ++i)
#pragma unroll
    for (int j = 0; j < 2; ++j)
#pragma unroll
      for (int r = 0; r < 16; ++r) acc[i][j][r] = 0.f;

  for (int kt = 0; kt < 8; ++kt) {
    {  // stage B (panel order: 4 contiguous streams)
      const unsigned short* gb = Wt + ((size_t)(cbk * 8 + kt) * 1024 + t) * 8;
#pragma unroll
      for (int i = 0; i < 4; ++i)
        GLOAD_LDS16(gb + (size_t)i * 2048, sB + (i * 256 + t) * 16);
    }
    {  // stage A rows: 8 lanes x 16B = 128B contiguous per row
      int jblk = kt >> 1;
      int inner = (kt & 1) * 64;
#pragma unroll
      for (int i = 0; i < 4; ++i) {
        int s = i * 256 + t;
        int r = s >> 3;
        int cl = (s & 7) ^ (r & 7);
        int src = sIdx[r * 4 + jblk];
        GLOAD_LDS16(A + (size_t)src * 128 + inner + cl * 8, sA + s * 16);
      }
    }
    __syncthreads();
#pragma unroll
    for (int ks = 0; ks < 4; ++ks) {
      short8 bfr[2];
#pragma unroll
      for (int j = 0; j < 2; ++j)
        bfr[j] = *(const short8*)(sB + (ks * 256 + (wnq + j) * 64 + l) * 16);
      short8 ag[2];
      int cbp = ((ks << 1) + half) ^ (m32 & 7);
#pragma unroll
      for (int i = 0; i < 2; ++i)
        ag[i] = *(const short8*)(sA + (wm + i * 32 + m32) * 128 + cbp * 16);
#pragma unroll
      for (int i = 0; i < 2; ++i)
#pragma unroll
        for (int j = 0; j < 2; ++j)
          acc[i][j] = __builtin_amdgcn_mfma_f32_32x32x16_bf16(
              ag[i], bfr[j], acc[i][j], 0, 0, 0);
    }
    __syncthreads();
  }

  // Epilogue. 32x32 C/D: col = lane&31, row = (reg&3) + 8*(reg>>2) + 4*half.
  unsigned short* L = (unsigned short*)smem;
#pragma unroll
  for (int i = 0; i < 2; ++i)
#pragma unroll
    for (int j = 0; j < 2; ++j) {
      int coll = wnq * 32 + j * 32 + m32;
      float bv = bias[n0 + coll];
#pragma unroll
      for (int r = 0; r < 16; ++r) {
        int rowl = wm + i * 32 + (r & 3) + 8 * (r >> 2) + 4 * half;
        float v = fmaxf(acc[i][j][r] + bv, 0.f);
        L[rowl * LSTR + coll] = f2bf(v);
      }
    }
  __syncthreads();

  // store to 256-row-panel X layout (this block = half of panel rb>>1)
  int mblk = rb >> 1, rhalf = (rb & 1) * 4;
#pragma unroll
  for (int it = 0; it < 8; ++it) {
    int c = it * 256 + t;     // 0..2047
    int ktl = c >> 10;        // 0..1 (cols cbk*128 span kt 2cbk..2cbk+1)
    int s = c & 1023;
    int ks = s >> 8, rg = (s >> 6) & 3, hf = (s >> 5) & 1, m = s & 31;
    ushort8 val =
        *(const ushort8*)(L + (rg * 32 + m) * LSTR + ktl * 64 + (ks * 2 + hf) * 8);
    *(ushort8*)(Xout + ((size_t)((mblk * 8 + cbk * 2 + ktl) * 2048) + ks * 512 +
                        (rhalf + rg) * 64 + hf * 32 + m) * 8) = val;
  }
}

// --- Dense gemm (layers 2,3): BM=256 x BN=128, per-wave 128x64, A direct ----
template <int FINAL>
__global__ __launch_bounds__(256, 2) void gemm_d(
    const unsigned short* __restrict__ A,   // X panel (256-row blocks)
    const unsigned short* __restrict__ Wt,  // R7 panel layout
    const float* __restrict__ bias,
    unsigned short* __restrict__ Xout,      // X panel (256-row blocks)
    float* __restrict__ out, const float* __restrict__ Wo,
    int mchunk0) {
  __shared__ __align__(16) char smem[36864];
  char* sB = smem;                       // 16384
  float* sWo = (float*)(smem + 35840);   // 1024 (FINAL)
  // epilogue L (128 x LSTR2) overlays smem[0..34816)

  const int t = threadIdx.x;
  int bx = blockIdx.x;
  int xcd = bx & 7, tq = bx >> 3;
  int cbk = tq & 3;
  int rb = xcd + ((tq >> 2) << 3);       // 256-row block index
  int n0 = cbk * 128;
  int w = t >> 6, l = t & 63;
  int wr = w >> 1, wc = w & 1;
  int wm32 = wr * 4;                     // row32-group base (wr*128/32)
  int m32 = l & 31, half = l >> 5;

  if (FINAL) sWo[t] = Wo[n0 * 2 + t];

  f32x16 acc[4][2];
#pragma unroll
  for (int i = 0; i < 4; ++i)
#pragma unroll
    for (int j = 0; j < 2; ++j)
#pragma unroll
      for (int r = 0; r < 16; ++r) acc[i][j][r] = 0.f;

  for (int kt = 0; kt < 8; ++kt) {
    // direct A-frag loads: lane-contiguous 1KB per (ks,mi); issued before
    // B staging so the barrier's vmcnt(0) covers their latency.
    short8 afr[4][4];
    const unsigned short* ga = A + (size_t)(rb * 8 + kt) * 16384;
#pragma unroll
    for (int ks = 0; ks < 4; ++ks)
#pragma unroll
      for (int mi = 0; mi < 4; ++mi)
        afr[ks][mi] = *(const short8*)(ga +
            (size_t)(ks * 512 + (wm32 + mi) * 64 + l) * 8);
    {  // stage B
      const unsigned short* gb = Wt + ((size_t)(cbk * 8 + kt) * 1024 + t) * 8;
#pragma unroll
      for (int i = 0; i < 4; ++i)
        GLOAD_LDS16(gb + (size_t)i * 2048, sB + (i * 256 + t) * 16);
    }
    __syncthreads();
#pragma unroll
    for (int ks = 0; ks < 4; ++ks) {
      short8 bfr[2];
#pragma unroll
      for (int j = 0; j < 2; ++j)
        bfr[j] = *(const short8*)(sB + (ks * 256 + (wc * 2 + j) * 64 + l) * 16);
#pragma unroll
      for (int mi = 0; mi < 4; ++mi)
#pragma unroll
        for (int j = 0; j < 2; ++j)
          acc[mi][j] = __builtin_amdgcn_mfma_f32_32x32x16_bf16(
              afr[ks][mi], bfr[j], acc[mi][j], 0, 0, 0);
    }
    __syncthreads();
  }

  // Two-pass epilogue (rows h*128..h*128+127), L = 128 x LSTR2 overlay.
  unsigned short* L = (unsigned short*)smem;
#pragma unroll
  for (int h = 0; h < 2; ++h) {
    if (wr == h) {
#pragma unroll
      for (int mi = 0; mi < 4; ++mi)
#pragma unroll
        for (int j = 0; j < 2; ++j) {
          int coll = wc * 64 + j * 32 + m32;
          float bv = bias[n0 + coll];
#pragma unroll
          for (int r = 0; r < 16; ++r) {
            int rowl = mi * 32 + (r & 3) + 8 * (r >> 2) + 4 * half;
            float v = fmaxf(acc[mi][j][r] + bv, 0.f);
            L[rowl * LSTR2 + coll] = f2bf(v);
          }
        }
    }
    __syncthreads();
    if (!FINAL) {
#pragma unroll
      for (int it = 0; it < 8; ++it) {
        int c = it * 256 + t;     // 0..2047
        int ktl = c >> 10;
        int s = c & 1023;
        int ks = s >> 8, rg = (s >> 6) & 3, hf = (s >> 5) & 1, m = s & 31;
        ushort8 val = *(const ushort8*)(L + (rg * 32 + m) * LSTR2 + ktl * 64 +
                                        (ks * 2 + hf) * 8);
        *(ushort8*)(Xout + ((size_t)((rb * 8 + cbk * 2 + ktl) * 2048) +
                            ks * 512 + (h * 4 + rg) * 64 + hf * 32 + m) * 8) =
            val;
      }
    } else {
      int r2 = t >> 1, jo = t & 1;
      int grow = mchunk0 + rb * 256 + h * 128 + r2;
      if (grow < MTOT) {
        const unsigned short* Lr = L + r2 * LSTR2;
        float sacc = 0.f;
#pragma unroll
        for (int cq = 0; cq < 16; ++cq) {
          ushort8 pv = *(const ushort8*)(Lr + cq * 8);
#pragma unroll
          for (int e = 0; e < 8; ++e)
            sacc += bf2f(pv[e]) * sWo[(cq * 8 + e) * 2 + jo];
        }
        int node = grow / 3;
        atomicAdd(out + node * 2 + jo, sacc);
      }
    }
    __syncthreads();
  }
}

extern "C" void kernel_launch(void* const* d_in, const int* in_sizes, int n_in,
                              void* d_out, int out_size, void* d_ws,
                              size_t ws_size, hipStream_t stream) {
  const float* h  = (const float*)d_in[0];
  const int*   ix = (const int*)d_in[1];
  const float* W1 = (const float*)d_in[2];
  const float* b1 = (const float*)d_in[3];
  const float* W2 = (const float*)d_in[4];
  const float* b2 = (const float*)d_in[5];
  const float* W3 = (const float*)d_in[6];
  const float* b3 = (const float*)d_in[7];
  const float* Wo = (const float*)d_in[8];
  const float* bo = (const float*)d_in[9];
  float* out = (float*)d_out;

  unsigned short* ws = (unsigned short*)d_ws;
  unsigned short* Wt = ws;                  // 3*512*512 shorts (panel)
  unsigned short* hb = Wt + 786432;         // 50000*128 shorts (row-major)
  unsigned short* bufs = hb + 6400000;
  const size_t baseBytes = (786432ull + 6400000ull) * 2;

  // nodes per chunk: multiple of 2048 -> rows%6144==0 -> RB256%24==0,
  // dense grid %32==0 and gather grid %32==0 (swizzle bijective)
  size_t avail = ws_size > baseBytes ? ws_size - baseBytes : 0;
  size_t ncap = avail / (2ull * 3 * HD * sizeof(unsigned short));
  size_t nc = (ncap / 2048) * 2048;
  if (nc > 32768) nc = 32768;
  if (nc == 0) nc = 2048;  // best effort
  unsigned short* X1 = bufs;                // panel layout
  unsigned short* X2 = X1 + nc * 3 * HD;    // panel layout

  prep_w<<<3072, 256, 0, stream>>>(W1, W2, W3, Wt);
  prep_hb<<<NH * 16 / 256, 256, 0, stream>>>(h, hb);
  init_out<<<(2 * NNODES + 255) / 256, 256, 0, stream>>>(out, bo);

  for (size_t n0c = 0; n0c < NNODES; n0c += nc) {
    size_t remn = (size_t)NNODES - n0c;
    size_t ncp = remn < nc ? ((remn + 2047) / 2048) * 2048 : nc;
    int rows = (int)(ncp * 3);
    int RBg = rows / 128;   // gather row-blocks
    int RBd = rows / 256;   // dense row-blocks
    int m0 = (int)(3 * n0c);
    gemm_g<<<RBg * 4, 256, 0, stream>>>(hb, ix, Wt, b1, X1, m0);
    gemm_d<0><<<RBd * 4, 256, 0, stream>>>(X1, Wt + 262144, b2, X2,
                                           nullptr, nullptr, 0);
    gemm_d<1><<<RBd * 4, 256, 0, stream>>>(X2, Wt + 524288, b3, nullptr,
                                           out, Wo, m0);
  }
}

// Round 4
// 665.969 us; speedup vs baseline: 1.5880x; 1.1258x over previous
//
#include <hip/hip_runtime.h>
#include <stdint.h>
#include <stddef.h>

// ---------------------------------------------------------------------------
// Round 11: exact R7 revert (the proven 666us structure: 3 chained GEMMs,
// 32x32x16 MFMA, 128x128 tile, BK=64, A-direct-from-global in dense gemms,
// LDS-staged gather A in gemm1) + ONE change: chunk cap 32768 -> 100352 so
// the whole problem runs as a single chunk (3 gemm dispatches, 36-deep grids)
// when workspace allows. R8-R10's structural rewrites (deep pipeline, wider
// tiles) all regressed: this problem's K=512 / shallow-grid regime is
// latency/barrier-bound and the 2-barrier + 4-blocks/CU structure is the
// measured local optimum; remaining waste was dispatch tails + runt chunk.
// ---------------------------------------------------------------------------

typedef __attribute__((ext_vector_type(8))) short short8;
typedef __attribute__((ext_vector_type(16))) float f32x16;
typedef __attribute__((ext_vector_type(4))) float floatv4;
typedef __attribute__((ext_vector_type(8))) unsigned short ushort8;

#define GLOAD_LDS16(g, l)                                                      \
  __builtin_amdgcn_global_load_lds(                                            \
      (const __attribute__((address_space(1))) void*)(g),                      \
      (__attribute__((address_space(3))) void*)(l), 16, 0, 0)

__device__ __forceinline__ unsigned short f2bf(float f) {
  unsigned int u = __float_as_uint(f);
  u += 0x7fffu + ((u >> 16) & 1u);  // RNE
  return (unsigned short)(u >> 16);
}
__device__ __forceinline__ float bf2f(unsigned short s) {
  return __uint_as_float(((unsigned int)s) << 16);
}

#define NNODES 100000
#define MTOT   300000
#define HD     512
#define NH     50000
#define LSTR   152   // L row stride in shorts: 304B = 19 x 16B (odd -> rotate)

// --- Wt in panel layout: per layer, per (nb,kt) panel of 1024 16B-slots -----
// slot s = (c>>1)*256 + ((row>>5)&3)*64 + (c&1)*32 + (row&31), c=k-granule 0..7
__global__ __launch_bounds__(256) void prep_w(const float* __restrict__ W1,
                                              const float* __restrict__ W2,
                                              const float* __restrict__ W3,
                                              unsigned short* __restrict__ Wt) {
  int t = blockIdx.x * 256 + threadIdx.x;  // < 3*512*512
  int layer = t >> 18;
  int r = t & 262143;
  int e = r & 7;
  int q16 = r >> 3;
  int s = q16 & 1023;
  int blk = q16 >> 10;        // 0..31
  int nb = blk >> 3, kt = blk & 7;
  int c = ((s >> 8) << 1) | ((s >> 5) & 1);
  int row = ((s >> 6) & 3) * 32 + (s & 31);
  int n = nb * 128 + row;
  int k = kt * 64 + c * 8 + e;
  const float* W = layer == 0 ? W1 : (layer == 1 ? W2 : W3);
  Wt[t] = f2bf(W[k * 512 + n]);
}

// --- hb = bf16(h) [50000 x 128], row-major ----------------------------------
__global__ __launch_bounds__(256) void prep_hb(const float* __restrict__ h,
                                               unsigned short* __restrict__ hb) {
  int t = blockIdx.x * 256 + threadIdx.x;  // < NH*16
  int v = t >> 4, c8 = (t & 15) * 8;
  const floatv4* hp = (const floatv4*)(h + (size_t)v * 128 + c8);
  floatv4 f0 = hp[0], f1 = hp[1];
  ushort8 o;
#pragma unroll
  for (int e = 0; e < 4; ++e) {
    o[e] = f2bf(f0[e]);
    o[4 + e] = f2bf(f1[e]);
  }
  *(ushort8*)(hb + (size_t)v * 128 + c8) = o;
}

__global__ __launch_bounds__(256) void init_out(float* __restrict__ out,
                                                const float* __restrict__ bo) {
  int t = blockIdx.x * 256 + threadIdx.x;
  if (t < 2 * NNODES) out[t] = bo[t & 1];
}

// --- GEMM: 128x128 tile, BK=64, K=512, 32x32x16 MFMA ------------------------
// GATHER: A staged via LDS from row-major hb (R4 pattern). Else: A read
// directly global->VGPR from panel-layout X. B always LDS (panel layout).
template <int GATHER, int FINAL>
__global__ __launch_bounds__(256, 4) void gemm_k(
    const unsigned short* __restrict__ A,   // GATHER ? hb(row-major) : X panel
    const int* __restrict__ idx,
    const unsigned short* __restrict__ Wt,  // panel layout
    const float* __restrict__ bias,
    unsigned short* __restrict__ Xout,      // panel layout
    float* __restrict__ out, const float* __restrict__ Wo,
    int mchunk0) {
  __shared__ __align__(16) char smem[39936];
  char* sB = smem;                       // 16384 (B tile, panel order)
  char* sA = smem + 16384;               // 16384 (GATHER only, row-major+XOR)
  int* sIdx = (int*)(smem + 32768);      // 2048  (GATHER only)
  float* sWo = (float*)(smem + 38912);   // 1024  (FINAL only)
  // epilogue L overlays smem[0..38912)

  const int t = threadIdx.x;
  int bx = blockIdx.x;
  // XCD swizzle: 4 col-blocks of one row-block land on one XCD.
  int xcd = bx & 7, tq = bx >> 3;
  int cbk = tq & 3;
  int rb = xcd + ((tq >> 2) << 3);
  int n0 = cbk * 128;
  int rb8 = rb * 8;
  int w = t >> 6, l = t & 63;
  int wmq = (w >> 1) * 2, wnq = (w & 1) * 2;   // 32-row-group bases
  int m32 = l & 31, half = l >> 5;
  int wm = wmq * 32;

  if (GATHER) {
    if (t < 128) {
      int m = mchunk0 + rb * 128 + t;
      unsigned um = (unsigned)m;
      unsigned n = um / 3u;
      int p = (int)(um - n * 3u);
      if (n >= NNODES) n = 0;  // padded tail rows: junk, guarded at output
      const unsigned pk0 = 0x320u, pk1 = 0x111u, pk2 = 0x032u, pk3 = 0x203u;
      int sh = p * 4;
      sIdx[t * 4 + 0] = idx[n * 4 + ((pk0 >> sh) & 0xFu)];
      sIdx[t * 4 + 1] = idx[n * 4 + ((pk1 >> sh) & 0xFu)];
      sIdx[t * 4 + 2] = idx[n * 4 + ((pk2 >> sh) & 0xFu)];
      sIdx[t * 4 + 3] = idx[n * 4 + ((pk3 >> sh) & 0xFu)];
    }
    __syncthreads();
  }

  f32x16 acc[2][2];
#pragma unroll
  for (int i = 0; i < 2; ++i)
#pragma unroll
    for (int j = 0; j < 2; ++j)
#pragma unroll
      for (int r = 0; r < 16; ++r) acc[i][j][r] = 0.f;

  for (int kt = 0; kt < 8; ++kt) {
    short8 afr[4][2];
    if (!GATHER) {
      // direct A-frag loads: lane-contiguous 1KB per (ks,i); issued before
      // B staging so the barrier's vmcnt(0) covers their latency.
      const unsigned short* ga = A + ((size_t)(rb8 + kt) * 1024) * 8;
#pragma unroll
      for (int ks = 0; ks < 4; ++ks)
#pragma unroll
        for (int i = 0; i < 2; ++i)
          afr[ks][i] = *(const short8*)(ga +
              (size_t)(ks * 256 + (wmq + i) * 64 + l) * 8);
    }
    {  // stage B (panel order: 4 contiguous streams)
      const unsigned short* gb = Wt + ((size_t)(cbk * 8 + kt) * 1024 + t) * 8;
#pragma unroll
      for (int i = 0; i < 4; ++i)
        GLOAD_LDS16(gb + (size_t)i * 2048, sB + (i * 256 + t) * 16);
    }
    if (GATHER) {  // stage A rows: 8 lanes x 16B = 128B contiguous per row
      int jblk = kt >> 1;
      int inner = (kt & 1) * 64;
#pragma unroll
      for (int i = 0; i < 4; ++i) {
        int s = i * 256 + t;
        int r = s >> 3;
        int cl = (s & 7) ^ (r & 7);
        int src = sIdx[r * 4 + jblk];
        GLOAD_LDS16(A + (size_t)src * 128 + inner + cl * 8, sA + s * 16);
      }
    }
    __syncthreads();
#pragma unroll
    for (int ks = 0; ks < 4; ++ks) {
      short8 bfr[2];
#pragma unroll
      for (int j = 0; j < 2; ++j)
        bfr[j] = *(const short8*)(sB + (ks * 256 + (wnq + j) * 64 + l) * 16);
      if (GATHER) {
        short8 ag[2];
        int cbp = ((ks << 1) + half) ^ (m32 & 7);
#pragma unroll
        for (int i = 0; i < 2; ++i)
          ag[i] = *(const short8*)(sA + (wm + i * 32 + m32) * 128 + cbp * 16);
#pragma unroll
        for (int i = 0; i < 2; ++i)
#pragma unroll
          for (int j = 0; j < 2; ++j)
            acc[i][j] = __builtin_amdgcn_mfma_f32_32x32x16_bf16(
                ag[i], bfr[j], acc[i][j], 0, 0, 0);
      } else {
#pragma unroll
        for (int i = 0; i < 2; ++i)
#pragma unroll
          for (int j = 0; j < 2; ++j)
            acc[i][j] = __builtin_amdgcn_mfma_f32_32x32x16_bf16(
                afr[ks][i], bfr[j], acc[i][j], 0, 0, 0);
      }
    }
    __syncthreads();
  }

  // Epilogue. 32x32 C/D: col = lane&31, row = (reg&3) + 8*(reg>>2) + 4*half.
  unsigned short* L = (unsigned short*)smem;
  if (FINAL && t < 256) sWo[t] = Wo[n0 * 2 + t];
#pragma unroll
  for (int i = 0; i < 2; ++i)
#pragma unroll
    for (int j = 0; j < 2; ++j) {
      int coll = wnq * 32 + j * 32 + m32;
      float bv = bias[n0 + coll];
#pragma unroll
      for (int r = 0; r < 16; ++r) {
        int rowl = wm + i * 32 + (r & 3) + 8 * (r >> 2) + 4 * half;
        float v = fmaxf(acc[i][j][r] + bv, 0.f);
        L[rowl * LSTR + coll] = f2bf(v);
      }
    }
  __syncthreads();

  if (!FINAL) {
    // panel-order coalesced stores: consecutive t -> consecutive 16B slots
#pragma unroll
    for (int v = 0; v < 8; ++v) {
      int chunk = v * 256 + t;          // 0..2047
      int ktsel = chunk >> 10;
      int s = chunk & 1023;
      int ks_l = s >> 8;
      int rowhi = (s >> 6) & 3;
      int hb_ = (s >> 5) & 1;
      int row = rowhi * 32 + (s & 31);
      int col_local = ktsel * 64 + (((ks_l << 1) | hb_) << 3);
      ushort8 val = *(const ushort8*)(L + row * LSTR + col_local);
      *(ushort8*)(Xout + ((size_t)(rb8 + 2 * cbk + ktsel) * 1024 + s) * 8) = val;
    }
  } else {
    int r2 = t >> 1, jo = t & 1;
    int grow = mchunk0 + rb * 128 + r2;
    if (grow < MTOT) {
      const unsigned short* Lr = L + r2 * LSTR;
      float s = 0.f;
#pragma unroll
      for (int cc = 0; cc < 128; cc += 2) {
        unsigned int pair = *(const unsigned int*)(Lr + cc);
        s += bf2f((unsigned short)(pair & 0xffffu)) * sWo[2 * cc + jo];
        s += bf2f((unsigned short)(pair >> 16)) * sWo[2 * cc + 2 + jo];
      }
      int node = grow / 3;
      atomicAdd(out + node * 2 + jo, s);
    }
  }
}

extern "C" void kernel_launch(void* const* d_in, const int* in_sizes, int n_in,
                              void* d_out, int out_size, void* d_ws,
                              size_t ws_size, hipStream_t stream) {
  const float* h  = (const float*)d_in[0];
  const int*   ix = (const int*)d_in[1];
  const float* W1 = (const float*)d_in[2];
  const float* b1 = (const float*)d_in[3];
  const float* W2 = (const float*)d_in[4];
  const float* b2 = (const float*)d_in[5];
  const float* W3 = (const float*)d_in[6];
  const float* b3 = (const float*)d_in[7];
  const float* Wo = (const float*)d_in[8];
  const float* bo = (const float*)d_in[9];
  float* out = (float*)d_out;

  unsigned short* ws = (unsigned short*)d_ws;
  unsigned short* Wt = ws;                  // 3*512*512 shorts (panel)
  unsigned short* hb = Wt + 786432;         // 50000*128 shorts (row-major)
  unsigned short* bufs = hb + 6400000;
  const size_t baseBytes = (786432ull + 6400000ull) * 2;

  // nodes per chunk: multiple of 2048 -> rows%6144==0 -> RB%48==0 (RB%8==0).
  // Cap 100352 (=49*2048) covers all 100000 nodes in ONE chunk when the
  // workspace allows (X1+X2 = 616 MB) -> 3 deep gemm dispatches instead of
  // 12 shallow ones. Falls back to smaller chunks adaptively otherwise.
  size_t avail = ws_size > baseBytes ? ws_size - baseBytes : 0;
  size_t ncap = avail / (2ull * 3 * HD * sizeof(unsigned short));
  size_t nc = (ncap / 2048) * 2048;
  if (nc > 100352) nc = 100352;
  if (nc == 0) nc = 2048;  // best effort
  unsigned short* X1 = bufs;                // panel layout
  unsigned short* X2 = X1 + nc * 3 * HD;    // panel layout

  prep_w<<<3072, 256, 0, stream>>>(W1, W2, W3, Wt);
  prep_hb<<<NH * 16 / 256, 256, 0, stream>>>(h, hb);
  init_out<<<(2 * NNODES + 255) / 256, 256, 0, stream>>>(out, bo);

  for (size_t n0c = 0; n0c < NNODES; n0c += nc) {
    size_t remn = (size_t)NNODES - n0c;
    size_t ncp = remn < nc ? ((remn + 2047) / 2048) * 2048 : nc;
    int rows = (int)(ncp * 3);
    int RB = rows / 128;
    int m0 = (int)(3 * n0c);
    gemm_k<1, 0><<<RB * 4, 256, 0, stream>>>(hb, ix, Wt, b1, X1, nullptr,
                                             nullptr, m0);
    gemm_k<0, 0><<<RB * 4, 256, 0, stream>>>(X1, nullptr, Wt + 262144, b2, X2,
                                             nullptr, nullptr, m0);
    gemm_k<0, 1><<<RB * 4, 256, 0, stream>>>(X2, nullptr, Wt + 524288, b3,
                                             nullptr, out, Wo, m0);
  }
}